// Round 1
// baseline (497.156 us; speedup 1.0000x reference)
//
#include <hip/hip_runtime.h>

#define CAP 64  // per-node edge capacity (Poisson(16): P(deg>64) ~ 1e-19)

// Build padded CSR: cnt[d] = in-degree, eidx[d*CAP + p] = src
__global__ __launch_bounds__(256) void k_count_fill(
    const int* __restrict__ ei, int E, int* __restrict__ cnt, int* __restrict__ eidx) {
  int e = blockIdx.x * 256 + threadIdx.x;
  if (e >= E) return;
  int s = ei[e];
  int d = ei[E + e];
  int p = atomicAdd(&cnt[d], 1);
  if (p < CAP) eidx[(size_t)d * CAP + p] = s;
}

// agg1[i] = mean over neighbors of x[src], one 64-lane wave per node (2 floats/lane)
__global__ __launch_bounds__(256) void k_agg1(
    const int* __restrict__ eidx, const int* __restrict__ cnt,
    const float* __restrict__ x, float* __restrict__ agg, int N) {
  int w = (blockIdx.x * 256 + threadIdx.x) >> 6;
  int lane = threadIdx.x & 63;
  if (w >= N) return;
  int deg = cnt[w];
  const int* el = eidx + (size_t)w * CAP;
  float sx = 0.f, sy = 0.f;
  int e = 0;
  for (; e + 4 <= deg; e += 4) {
    int4 q = *(const int4*)(el + e);
    float2 v0 = *(const float2*)(x + (size_t)q.x * 128 + lane * 2);
    float2 v1 = *(const float2*)(x + (size_t)q.y * 128 + lane * 2);
    float2 v2 = *(const float2*)(x + (size_t)q.z * 128 + lane * 2);
    float2 v3 = *(const float2*)(x + (size_t)q.w * 128 + lane * 2);
    sx += v0.x + v1.x + v2.x + v3.x;
    sy += v0.y + v1.y + v2.y + v3.y;
  }
  for (; e < deg; ++e) {
    int s = el[e];
    float2 v = *(const float2*)(x + (size_t)s * 128 + lane * 2);
    sx += v.x; sy += v.y;
  }
  float sc = 1.0f / (float)max(deg, 1);
  float2 o; o.x = sx * sc; o.y = sy * sc;
  *(float2*)(agg + (size_t)w * 128 + lane * 2) = o;
}

// h = relu(agg1 @ W1l^T + x @ W1r^T + b1), rows padded to Np (pad rows clamp-read row N-1)
// 64 rows x 128 cols per block; thread (cg=t%32, rg=t/32) owns cols cg+32c, rows rg*8+r
__global__ __launch_bounds__(256) void k_gemm1(
    const float* __restrict__ agg1, const float* __restrict__ x,
    const float* __restrict__ W1l, const float* __restrict__ W1r,
    const float* __restrict__ b1, float* __restrict__ h, int N) {
  __shared__ float4 Ws[8][128];  // [k4][col], 16 KB: conflict-free b128 reads
  __shared__ float4 As[64][8];   // [row][k4], 8 KB: broadcast b128 reads
  const int t = threadIdx.x;
  const int cg = t & 31;
  const int rg = t >> 5;
  const int row0 = blockIdx.x * 64;
  float acc[8][4];
#pragma unroll
  for (int r = 0; r < 8; ++r)
#pragma unroll
    for (int c = 0; c < 4; ++c) acc[r][c] = 0.f;

  for (int phase = 0; phase < 2; ++phase) {
    const float* A = phase ? x : agg1;
    const float* W = phase ? W1r : W1l;
    for (int kc = 0; kc < 4; ++kc) {
      int k0 = kc * 32;
      __syncthreads();
#pragma unroll
      for (int i = 0; i < 4; ++i) {  // stage W chunk: 128 cols x 32 k
        int j = t + i * 256;
        int col = j >> 3, kq = j & 7;
        Ws[kq][col] = *(const float4*)(W + col * 128 + k0 + kq * 4);
      }
#pragma unroll
      for (int i = 0; i < 2; ++i) {  // stage A chunk: 64 rows x 32 k
        int j = t + i * 256;
        int row = j >> 3, kq = j & 7;
        int gr = row0 + row; if (gr > N - 1) gr = N - 1;
        As[row][kq] = *(const float4*)(A + (size_t)gr * 128 + k0 + kq * 4);
      }
      __syncthreads();
#pragma unroll
      for (int k4 = 0; k4 < 8; ++k4) {
        float4 w4[4];
#pragma unroll
        for (int c = 0; c < 4; ++c) w4[c] = Ws[k4][cg + 32 * c];
#pragma unroll
        for (int r = 0; r < 8; ++r) {
          float4 a4 = As[rg * 8 + r][k4];
#pragma unroll
          for (int c = 0; c < 4; ++c) {
            acc[r][c] = fmaf(a4.x, w4[c].x, acc[r][c]);
            acc[r][c] = fmaf(a4.y, w4[c].y, acc[r][c]);
            acc[r][c] = fmaf(a4.z, w4[c].z, acc[r][c]);
            acc[r][c] = fmaf(a4.w, w4[c].w, acc[r][c]);
          }
        }
      }
    }
  }
  float bv[4];
#pragma unroll
  for (int c = 0; c < 4; ++c) bv[c] = b1[cg + 32 * c];
#pragma unroll
  for (int r = 0; r < 8; ++r) {
    int gr = row0 + rg * 8 + r;
    float* hp = h + (size_t)gr * 128;
#pragma unroll
    for (int c = 0; c < 4; ++c) {
      float v = acc[r][c] + bv[c];
      hp[cg + 32 * c] = v > 0.f ? v : 0.f;
    }
  }
}

// Fold classifier into layer-2 weights: M[0:16]=Wc@W2l, M[16:32]=Wc@W2r (each 16x128),
// bias2 = Wc@b2l + bc
__global__ __launch_bounds__(256) void k_precomp(
    const float* __restrict__ Wc, const float* __restrict__ bc,
    const float* __restrict__ W2l, const float* __restrict__ W2r,
    const float* __restrict__ b2, float* __restrict__ M, float* __restrict__ bias2) {
  int b = blockIdx.x;  // 0..15
  int t = threadIdx.x;
  int mat = b >> 3;
  const float* W2 = mat ? W2r : W2l;
  int o = (b & 7) * 2 + (t >> 7);
  int k = t & 127;
  float s = 0.f;
  for (int j = 0; j < 128; ++j) s = fmaf(Wc[o * 128 + j], W2[j * 128 + k], s);
  M[(size_t)(mat * 16 + o) * 128 + k] = s;
  if (b == 0 && t < 16) {
    float sb = bc[t];
    for (int j = 0; j < 128; ++j) sb = fmaf(Wc[t * 128 + j], b2[j], sb);
    bias2[t] = sb;
  }
}

// P[N][32] = h @ M^T  (cols 0..15 feed aggregation, 16..31 are the self path)
__global__ __launch_bounds__(256) void k_gemm2(
    const float* __restrict__ h, const float* __restrict__ M,
    float* __restrict__ P, int N) {
  __shared__ float4 Ms[32][32];  // [k4][col] 16 KB
  __shared__ float4 As[64][32];  // [row][k4] 32 KB
  int t = threadIdx.x;
  int col = t & 31;
  int rg = t >> 5;
  int row0 = blockIdx.x * 64;
#pragma unroll
  for (int i = 0; i < 4; ++i) {
    int j = t + i * 256;
    int mc = j >> 5, k4 = j & 31;
    Ms[k4][mc] = *(const float4*)(M + (size_t)mc * 128 + k4 * 4);
  }
#pragma unroll
  for (int i = 0; i < 8; ++i) {
    int j = t + i * 256;
    int row = j >> 5, k4 = j & 31;
    As[row][k4] = *(const float4*)(h + (size_t)(row0 + row) * 128 + k4 * 4);
  }
  __syncthreads();
  float acc[8];
#pragma unroll
  for (int r = 0; r < 8; ++r) acc[r] = 0.f;
  for (int k4 = 0; k4 < 32; ++k4) {
    float4 w4 = Ms[k4][col];
#pragma unroll
    for (int r = 0; r < 8; ++r) {
      float4 a4 = As[rg * 8 + r][k4];
      acc[r] = fmaf(a4.x, w4.x, fmaf(a4.y, w4.y, fmaf(a4.z, w4.z, fmaf(a4.w, w4.w, acc[r]))));
    }
  }
#pragma unroll
  for (int r = 0; r < 8; ++r)
    P[(size_t)(row0 + rg * 8 + r) * 32 + col] = acc[r];
}

// out[i] = mean_nbr(P[src][0:16]) + P[i][16:32] + bias2 ; 16 lanes per node
__global__ __launch_bounds__(256) void k_agg2_out(
    const int* __restrict__ eidx, const int* __restrict__ cnt,
    const float* __restrict__ P, const float* __restrict__ bias2,
    float* __restrict__ out, int N) {
  int i = (blockIdx.x * 256 + threadIdx.x) >> 4;
  int f = threadIdx.x & 15;
  if (i >= N) return;
  int deg = cnt[i];
  const int* el = eidx + (size_t)i * CAP;
  float s = 0.f;
  int e = 0;
  for (; e + 4 <= deg; e += 4) {
    int4 q = *(const int4*)(el + e);
    s += P[(size_t)q.x * 32 + f] + P[(size_t)q.y * 32 + f] +
         P[(size_t)q.z * 32 + f] + P[(size_t)q.w * 32 + f];
  }
  for (; e < deg; ++e) s += P[(size_t)el[e] * 32 + f];
  float sc = 1.0f / (float)max(deg, 1);
  out[(size_t)i * 16 + f] = s * sc + P[(size_t)i * 32 + 16 + f] + bias2[f];
}

extern "C" void kernel_launch(void* const* d_in, const int* in_sizes, int n_in,
                              void* d_out, int out_size, void* d_ws, size_t ws_size,
                              hipStream_t stream) {
  const float* x   = (const float*)d_in[0];
  const int*   ei  = (const int*)d_in[1];
  const float* W1l = (const float*)d_in[2];
  const float* b1l = (const float*)d_in[3];
  const float* W1r = (const float*)d_in[4];
  const float* W2l = (const float*)d_in[5];
  const float* b2l = (const float*)d_in[6];
  const float* W2r = (const float*)d_in[7];
  const float* Wc  = (const float*)d_in[8];
  const float* bc  = (const float*)d_in[9];
  float* out = (float*)d_out;

  const int N  = in_sizes[0] / 128;
  const int E  = in_sizes[1] / 2;
  const int Np = ((N + 63) / 64) * 64;

  char* ws = (char*)d_ws;
  size_t off = 0;
  auto alloc = [&](size_t bytes) {
    void* p = ws + off;
    off = (off + bytes + 255) & ~(size_t)255;
    return p;
  };
  int*   cnt   = (int*)  alloc((size_t)N * 4);
  int*   eidx  = (int*)  alloc((size_t)N * CAP * 4);
  float* agg1  = (float*)alloc((size_t)Np * 128 * 4);
  float* h     = (float*)alloc((size_t)Np * 128 * 4);
  float* P     = (float*)alloc((size_t)Np * 32 * 4);
  float* M     = (float*)alloc((size_t)32 * 128 * 4);
  float* bias2 = (float*)alloc(16 * 4);
  (void)ws_size; (void)n_in; (void)out_size;

  hipMemsetAsync(cnt, 0, (size_t)N * 4, stream);
  k_count_fill<<<(E + 255) / 256, 256, 0, stream>>>(ei, E, cnt, eidx);
  k_precomp<<<16, 256, 0, stream>>>(Wc, bc, W2l, W2r, b2l, M, bias2);
  k_agg1<<<(N + 3) / 4, 256, 0, stream>>>(eidx, cnt, x, agg1, N);
  k_gemm1<<<Np / 64, 256, 0, stream>>>(agg1, x, W1l, W1r, b1l, h, N);
  k_gemm2<<<Np / 64, 256, 0, stream>>>(h, M, P, N);
  k_agg2_out<<<(N + 15) / 16, 256, 0, stream>>>(eidx, cnt, P, bias2, out, N);
}

// Round 2
// 465.915 us; speedup vs baseline: 1.0671x; 1.0671x over previous
//
#include <hip/hip_runtime.h>

#define CAP 64    // per-node edge capacity (Poisson(16): P(deg>64) ~ 1e-19)
#define NPART 8   // one dst-range partition per XCD (blockIdx % 8 ~ XCD id)

// XCD-partitioned padded-CSR build. Block b handles dst-partition b&7 and a
// chunk of edges. Each partition's write set (12.5k nodes * 256 B = 3.2 MB of
// eidx + 50 KB of cnt) fits one XCD's 4 MB L2, so the ~16 scattered 4B stores
// per cache line merge in L2 instead of each causing a partial-line eviction.
__global__ __launch_bounds__(256) void k_fill_part(
    const int* __restrict__ ei, int E, int nodes_per_part,
    int* __restrict__ cnt, int* __restrict__ eidx) {
  const int part = blockIdx.x & (NPART - 1);
  const int cb = blockIdx.x >> 3;
  const int ncb = gridDim.x >> 3;
  const int lo = part * nodes_per_part;
  const int hi = lo + nodes_per_part;
  const int* __restrict__ src = ei;
  const int* __restrict__ dst = ei + E;
  const int G = E >> 2;  // int4 groups
  for (int g = cb * 256 + threadIdx.x; g < G; g += ncb * 256) {
    int4 d4 = ((const int4*)dst)[g];
    int e0 = g * 4;
    if (d4.x >= lo && d4.x < hi) {
      int p = atomicAdd(&cnt[d4.x], 1);
      if (p < CAP) eidx[(size_t)d4.x * CAP + p] = src[e0];
    }
    if (d4.y >= lo && d4.y < hi) {
      int p = atomicAdd(&cnt[d4.y], 1);
      if (p < CAP) eidx[(size_t)d4.y * CAP + p] = src[e0 + 1];
    }
    if (d4.z >= lo && d4.z < hi) {
      int p = atomicAdd(&cnt[d4.z], 1);
      if (p < CAP) eidx[(size_t)d4.z * CAP + p] = src[e0 + 2];
    }
    if (d4.w >= lo && d4.w < hi) {
      int p = atomicAdd(&cnt[d4.w], 1);
      if (p < CAP) eidx[(size_t)d4.w * CAP + p] = src[e0 + 3];
    }
  }
  if (cb == 0) {  // tail edges (E not multiple of 4)
    for (int e = G * 4 + threadIdx.x; e < E; e += 256) {
      int d = dst[e];
      if (d >= lo && d < hi) {
        int p = atomicAdd(&cnt[d], 1);
        if (p < CAP) eidx[(size_t)d * CAP + p] = src[e];
      }
    }
  }
}

// agg1[i] = mean over neighbors of x[src], one 64-lane wave per node (2 floats/lane)
__global__ __launch_bounds__(256) void k_agg1(
    const int* __restrict__ eidx, const int* __restrict__ cnt,
    const float* __restrict__ x, float* __restrict__ agg, int N) {
  int w = (blockIdx.x * 256 + threadIdx.x) >> 6;
  int lane = threadIdx.x & 63;
  if (w >= N) return;
  int deg = cnt[w];
  const int* el = eidx + (size_t)w * CAP;
  float sx = 0.f, sy = 0.f;
  int e = 0;
  for (; e + 4 <= deg; e += 4) {
    int4 q = *(const int4*)(el + e);
    float2 v0 = *(const float2*)(x + (size_t)q.x * 128 + lane * 2);
    float2 v1 = *(const float2*)(x + (size_t)q.y * 128 + lane * 2);
    float2 v2 = *(const float2*)(x + (size_t)q.z * 128 + lane * 2);
    float2 v3 = *(const float2*)(x + (size_t)q.w * 128 + lane * 2);
    sx += v0.x + v1.x + v2.x + v3.x;
    sy += v0.y + v1.y + v2.y + v3.y;
  }
  for (; e < deg; ++e) {
    int s = el[e];
    float2 v = *(const float2*)(x + (size_t)s * 128 + lane * 2);
    sx += v.x; sy += v.y;
  }
  float sc = 1.0f / (float)max(deg, 1);
  float2 o; o.x = sx * sc; o.y = sy * sc;
  *(float2*)(agg + (size_t)w * 128 + lane * 2) = o;
}

// h = relu(agg1 @ W1l^T + x @ W1r^T + b1), rows padded to Np (pad rows clamp-read row N-1)
// 64 rows x 128 cols per block; thread (cg=t%32, rg=t/32) owns cols cg+32c, rows rg*8+r
__global__ __launch_bounds__(256) void k_gemm1(
    const float* __restrict__ agg1, const float* __restrict__ x,
    const float* __restrict__ W1l, const float* __restrict__ W1r,
    const float* __restrict__ b1, float* __restrict__ h, int N) {
  __shared__ float4 Ws[8][128];  // [k4][col], 16 KB: conflict-free b128 reads
  __shared__ float4 As[64][8];   // [row][k4], 8 KB: broadcast b128 reads
  const int t = threadIdx.x;
  const int cg = t & 31;
  const int rg = t >> 5;
  const int row0 = blockIdx.x * 64;
  float acc[8][4];
#pragma unroll
  for (int r = 0; r < 8; ++r)
#pragma unroll
    for (int c = 0; c < 4; ++c) acc[r][c] = 0.f;

  for (int phase = 0; phase < 2; ++phase) {
    const float* A = phase ? x : agg1;
    const float* W = phase ? W1r : W1l;
    for (int kc = 0; kc < 4; ++kc) {
      int k0 = kc * 32;
      __syncthreads();
#pragma unroll
      for (int i = 0; i < 4; ++i) {  // stage W chunk: 128 cols x 32 k
        int j = t + i * 256;
        int col = j >> 3, kq = j & 7;
        Ws[kq][col] = *(const float4*)(W + col * 128 + k0 + kq * 4);
      }
#pragma unroll
      for (int i = 0; i < 2; ++i) {  // stage A chunk: 64 rows x 32 k
        int j = t + i * 256;
        int row = j >> 3, kq = j & 7;
        int gr = row0 + row; if (gr > N - 1) gr = N - 1;
        As[row][kq] = *(const float4*)(A + (size_t)gr * 128 + k0 + kq * 4);
      }
      __syncthreads();
#pragma unroll
      for (int k4 = 0; k4 < 8; ++k4) {
        float4 w4[4];
#pragma unroll
        for (int c = 0; c < 4; ++c) w4[c] = Ws[k4][cg + 32 * c];
#pragma unroll
        for (int r = 0; r < 8; ++r) {
          float4 a4 = As[rg * 8 + r][k4];
#pragma unroll
          for (int c = 0; c < 4; ++c) {
            acc[r][c] = fmaf(a4.x, w4[c].x, acc[r][c]);
            acc[r][c] = fmaf(a4.y, w4[c].y, acc[r][c]);
            acc[r][c] = fmaf(a4.z, w4[c].z, acc[r][c]);
            acc[r][c] = fmaf(a4.w, w4[c].w, acc[r][c]);
          }
        }
      }
    }
  }
  float bv[4];
#pragma unroll
  for (int c = 0; c < 4; ++c) bv[c] = b1[cg + 32 * c];
#pragma unroll
  for (int r = 0; r < 8; ++r) {
    int gr = row0 + rg * 8 + r;
    float* hp = h + (size_t)gr * 128;
#pragma unroll
    for (int c = 0; c < 4; ++c) {
      float v = acc[r][c] + bv[c];
      hp[cg + 32 * c] = v > 0.f ? v : 0.f;
    }
  }
}

// Fold classifier into layer-2 weights: M[0:16]=Wc@W2l, M[16:32]=Wc@W2r (each 16x128),
// bias2 = Wc@b2l + bc
__global__ __launch_bounds__(256) void k_precomp(
    const float* __restrict__ Wc, const float* __restrict__ bc,
    const float* __restrict__ W2l, const float* __restrict__ W2r,
    const float* __restrict__ b2, float* __restrict__ M, float* __restrict__ bias2) {
  int b = blockIdx.x;  // 0..15
  int t = threadIdx.x;
  int mat = b >> 3;
  const float* W2 = mat ? W2r : W2l;
  int o = (b & 7) * 2 + (t >> 7);
  int k = t & 127;
  float s = 0.f;
  for (int j = 0; j < 128; ++j) s = fmaf(Wc[o * 128 + j], W2[j * 128 + k], s);
  M[(size_t)(mat * 16 + o) * 128 + k] = s;
  if (b == 0 && t < 16) {
    float sb = bc[t];
    for (int j = 0; j < 128; ++j) sb = fmaf(Wc[t * 128 + j], b2[j], sb);
    bias2[t] = sb;
  }
}

// P[N][32] = h @ M^T  (cols 0..15 feed aggregation, 16..31 are the self path)
__global__ __launch_bounds__(256) void k_gemm2(
    const float* __restrict__ h, const float* __restrict__ M,
    float* __restrict__ P, int N) {
  __shared__ float4 Ms[32][32];  // [k4][col] 16 KB
  __shared__ float4 As[64][32];  // [row][k4] 32 KB
  int t = threadIdx.x;
  int col = t & 31;
  int rg = t >> 5;
  int row0 = blockIdx.x * 64;
#pragma unroll
  for (int i = 0; i < 4; ++i) {
    int j = t + i * 256;
    int mc = j >> 5, k4 = j & 31;
    Ms[k4][mc] = *(const float4*)(M + (size_t)mc * 128 + k4 * 4);
  }
#pragma unroll
  for (int i = 0; i < 8; ++i) {
    int j = t + i * 256;
    int row = j >> 5, k4 = j & 31;
    As[row][k4] = *(const float4*)(h + (size_t)(row0 + row) * 128 + k4 * 4);
  }
  __syncthreads();
  float acc[8];
#pragma unroll
  for (int r = 0; r < 8; ++r) acc[r] = 0.f;
  for (int k4 = 0; k4 < 32; ++k4) {
    float4 w4 = Ms[k4][col];
#pragma unroll
    for (int r = 0; r < 8; ++r) {
      float4 a4 = As[rg * 8 + r][k4];
      acc[r] = fmaf(a4.x, w4.x, fmaf(a4.y, w4.y, fmaf(a4.z, w4.z, fmaf(a4.w, w4.w, acc[r]))));
    }
  }
#pragma unroll
  for (int r = 0; r < 8; ++r)
    P[(size_t)(row0 + rg * 8 + r) * 32 + col] = acc[r];
}

// out[i] = mean_nbr(P[src][0:16]) + P[i][16:32] + bias2 ; 16 lanes per node
__global__ __launch_bounds__(256) void k_agg2_out(
    const int* __restrict__ eidx, const int* __restrict__ cnt,
    const float* __restrict__ P, const float* __restrict__ bias2,
    float* __restrict__ out, int N) {
  int i = (blockIdx.x * 256 + threadIdx.x) >> 4;
  int f = threadIdx.x & 15;
  if (i >= N) return;
  int deg = cnt[i];
  const int* el = eidx + (size_t)i * CAP;
  float s = 0.f;
  int e = 0;
  for (; e + 4 <= deg; e += 4) {
    int4 q = *(const int4*)(el + e);
    s += P[(size_t)q.x * 32 + f] + P[(size_t)q.y * 32 + f] +
         P[(size_t)q.z * 32 + f] + P[(size_t)q.w * 32 + f];
  }
  for (; e < deg; ++e) s += P[(size_t)el[e] * 32 + f];
  float sc = 1.0f / (float)max(deg, 1);
  out[(size_t)i * 16 + f] = s * sc + P[(size_t)i * 32 + 16 + f] + bias2[f];
}

extern "C" void kernel_launch(void* const* d_in, const int* in_sizes, int n_in,
                              void* d_out, int out_size, void* d_ws, size_t ws_size,
                              hipStream_t stream) {
  const float* x   = (const float*)d_in[0];
  const int*   ei  = (const int*)d_in[1];
  const float* W1l = (const float*)d_in[2];
  const float* b1l = (const float*)d_in[3];
  const float* W1r = (const float*)d_in[4];
  const float* W2l = (const float*)d_in[5];
  const float* b2l = (const float*)d_in[6];
  const float* W2r = (const float*)d_in[7];
  const float* Wc  = (const float*)d_in[8];
  const float* bc  = (const float*)d_in[9];
  float* out = (float*)d_out;

  const int N  = in_sizes[0] / 128;
  const int E  = in_sizes[1] / 2;
  const int Np = ((N + 63) / 64) * 64;
  const int nodes_per_part = (N + NPART - 1) / NPART;

  char* ws = (char*)d_ws;
  size_t off = 0;
  auto alloc = [&](size_t bytes) {
    void* p = ws + off;
    off = (off + bytes + 255) & ~(size_t)255;
    return p;
  };
  int*   cnt   = (int*)  alloc((size_t)N * 4);
  int*   eidx  = (int*)  alloc((size_t)N * CAP * 4);
  float* agg1  = (float*)alloc((size_t)Np * 128 * 4);
  float* h     = (float*)alloc((size_t)Np * 128 * 4);
  float* P     = (float*)alloc((size_t)Np * 32 * 4);
  float* M     = (float*)alloc((size_t)32 * 128 * 4);
  float* bias2 = (float*)alloc(16 * 4);
  (void)ws_size; (void)n_in; (void)out_size;

  hipMemsetAsync(cnt, 0, (size_t)N * 4, stream);
  // 8 partitions x 128 edge-chunks; consecutive blocks -> different XCDs
  k_fill_part<<<NPART * 128, 256, 0, stream>>>(ei, E, nodes_per_part, cnt, eidx);
  k_precomp<<<16, 256, 0, stream>>>(Wc, bc, W2l, W2r, b2l, M, bias2);
  k_agg1<<<(N + 3) / 4, 256, 0, stream>>>(eidx, cnt, x, agg1, N);
  k_gemm1<<<Np / 64, 256, 0, stream>>>(agg1, x, W1l, W1r, b1l, h, N);
  k_gemm2<<<Np / 64, 256, 0, stream>>>(h, M, P, N);
  k_agg2_out<<<(N + 15) / 16, 256, 0, stream>>>(eidx, cnt, P, bias2, out, N);
}

// Round 3
// 357.601 us; speedup vs baseline: 1.3903x; 1.3029x over previous
//
#include <hip/hip_runtime.h>

#define CAP 64    // per-node edge capacity (Poisson(16): P(deg>64) ~ 1e-19)
#define NPART 8   // one dst-range partition per XCD (blockIdx % 8 ~ XCD id)

typedef __bf16 bf16x8 __attribute__((ext_vector_type(8)));
typedef float  f32x4  __attribute__((ext_vector_type(4)));

__device__ __forceinline__ unsigned short f2b(float f) {  // fp32 -> bf16 RNE
  unsigned u = __float_as_uint(f);
  return (unsigned short)((u + 0x7fffu + ((u >> 16) & 1u)) >> 16);
}
__device__ __forceinline__ float b2f_lo(unsigned u) {  // low bf16 of packed pair
  return __uint_as_float(u << 16);
}
__device__ __forceinline__ float b2f_hi(unsigned u) {
  return __uint_as_float(u & 0xffff0000u);
}

// ---------------------------------------------------------------- CSR build
__global__ __launch_bounds__(256) void k_fill_part(
    const int* __restrict__ ei, int E, int nodes_per_part,
    int* __restrict__ cnt, int* __restrict__ eidx) {
  const int part = blockIdx.x & (NPART - 1);
  const int cb = blockIdx.x >> 3;
  const int ncb = gridDim.x >> 3;
  const int lo = part * nodes_per_part;
  const int hi = lo + nodes_per_part;
  const int* __restrict__ src = ei;
  const int* __restrict__ dst = ei + E;
  const int G = E >> 2;
  for (int g = cb * 256 + threadIdx.x; g < G; g += ncb * 256) {
    int4 d4 = ((const int4*)dst)[g];
    int e0 = g * 4;
    if (d4.x >= lo && d4.x < hi) {
      int p = atomicAdd(&cnt[d4.x], 1);
      if (p < CAP) eidx[(size_t)d4.x * CAP + p] = src[e0];
    }
    if (d4.y >= lo && d4.y < hi) {
      int p = atomicAdd(&cnt[d4.y], 1);
      if (p < CAP) eidx[(size_t)d4.y * CAP + p] = src[e0 + 1];
    }
    if (d4.z >= lo && d4.z < hi) {
      int p = atomicAdd(&cnt[d4.z], 1);
      if (p < CAP) eidx[(size_t)d4.z * CAP + p] = src[e0 + 2];
    }
    if (d4.w >= lo && d4.w < hi) {
      int p = atomicAdd(&cnt[d4.w], 1);
      if (p < CAP) eidx[(size_t)d4.w * CAP + p] = src[e0 + 3];
    }
  }
  if (cb == 0) {
    for (int e = G * 4 + threadIdx.x; e < E; e += 256) {
      int d = dst[e];
      if (d >= lo && d < hi) {
        int p = atomicAdd(&cnt[d], 1);
        if (p < CAP) eidx[(size_t)d * CAP + p] = src[e];
      }
    }
  }
}

// ---------------------------------------------------------------- casts
// x (fp32) -> xb (bf16), one float4 per thread
__global__ __launch_bounds__(256) void k_cast(
    const float* __restrict__ x, unsigned short* __restrict__ xb, int ngroups) {
  int g = blockIdx.x * 256 + threadIdx.x;
  if (g >= ngroups) return;
  float4 v = ((const float4*)x)[g];
  ushort4 o;
  o.x = f2b(v.x); o.y = f2b(v.y); o.z = f2b(v.z); o.w = f2b(v.w);
  ((ushort4*)xb)[g] = o;
}

// Wb[col][k] bf16, k<128 from W1l, k>=128 from W1r (both stored [col][k] fp32)
__global__ __launch_bounds__(256) void k_castW(
    const float* __restrict__ W1l, const float* __restrict__ W1r,
    unsigned short* __restrict__ Wb) {
  int idx = blockIdx.x * 256 + threadIdx.x;  // 128*256 = 32768 total
  int col = idx >> 8, k = idx & 255;
  float v = (k < 128) ? W1l[col * 128 + k] : W1r[col * 128 + (k - 128)];
  Wb[col * 256 + k] = f2b(v);
}

// ---------------------------------------------------------------- agg1 (bf16)
// aggb[i] = bf16(mean over neighbors of xb[src]); lane handles bf16 pair lane*2
__global__ __launch_bounds__(256) void k_agg1(
    const int* __restrict__ eidx, const int* __restrict__ cnt,
    const unsigned short* __restrict__ xb, unsigned short* __restrict__ aggb, int N) {
  int w = (blockIdx.x * 256 + threadIdx.x) >> 6;
  int lane = threadIdx.x & 63;
  if (w >= N) return;
  int deg = cnt[w];
  const int* el = eidx + (size_t)w * CAP;
  float s0 = 0.f, s1 = 0.f;
  int e = 0;
  for (; e + 4 <= deg; e += 4) {
    int4 q = *(const int4*)(el + e);
    unsigned u0 = *(const unsigned*)(xb + (size_t)q.x * 128 + lane * 2);
    unsigned u1 = *(const unsigned*)(xb + (size_t)q.y * 128 + lane * 2);
    unsigned u2 = *(const unsigned*)(xb + (size_t)q.z * 128 + lane * 2);
    unsigned u3 = *(const unsigned*)(xb + (size_t)q.w * 128 + lane * 2);
    s0 += b2f_lo(u0) + b2f_lo(u1) + b2f_lo(u2) + b2f_lo(u3);
    s1 += b2f_hi(u0) + b2f_hi(u1) + b2f_hi(u2) + b2f_hi(u3);
  }
  for (; e < deg; ++e) {
    unsigned u = *(const unsigned*)(xb + (size_t)el[e] * 128 + lane * 2);
    s0 += b2f_lo(u); s1 += b2f_hi(u);
  }
  float sc = 1.0f / (float)max(deg, 1);
  unsigned o = (unsigned)f2b(s0 * sc) | ((unsigned)f2b(s1 * sc) << 16);
  *(unsigned*)(aggb + (size_t)w * 128 + lane * 2) = o;
}

// ---------------------------------------------------------------- gemm1 MFMA
// h = relu([aggb | xb] @ Wb^T + b1)  (K=256, bf16 in / fp32 out)
// Block: 128 rows x 128 cols, 4 waves; wave w owns rows [w*32, w*32+32).
// LDS rows padded to 40 bf16 (80 B) -> <=2-way bank aliasing (free, m136).
__global__ __launch_bounds__(256) void k_gemm1_mfma(
    const unsigned short* __restrict__ aggb, const unsigned short* __restrict__ xb,
    const unsigned short* __restrict__ Wb, const float* __restrict__ b1,
    float* __restrict__ h, int N) {
  __shared__ unsigned short Alds[128 * 40];  // 10 KB
  __shared__ unsigned short Wlds[128 * 40];  // 10 KB
  const int t = threadIdx.x;
  const int w = t >> 6;
  const int lane = t & 63;
  const int q = lane >> 4;       // k-quad of the fragment
  const int l16 = lane & 15;
  const int row0 = blockIdx.x * 128;

  f32x4 acc[2][8];
#pragma unroll
  for (int rt = 0; rt < 2; ++rt)
#pragma unroll
    for (int ct = 0; ct < 8; ++ct) acc[rt][ct] = (f32x4){0.f, 0.f, 0.f, 0.f};

  for (int kc = 0; kc < 8; ++kc) {
    const unsigned short* Asrc = (kc < 4) ? aggb : xb;
    const int koff = (kc & 3) * 32;
#pragma unroll
    for (int i = 0; i < 2; ++i) {  // stage A: 128 rows x 32 k (8 KB)
      int idx = t + i * 256;
      int row = idx >> 2, c4 = idx & 3;
      int gr = row0 + row; if (gr >= N) gr = N - 1;
      uint4 v = *(const uint4*)(Asrc + (size_t)gr * 128 + koff + c4 * 8);
      *(uint4*)(Alds + row * 40 + c4 * 8) = v;
    }
#pragma unroll
    for (int i = 0; i < 2; ++i) {  // stage W: 128 cols x 32 k (8 KB)
      int idx = t + i * 256;
      int col = idx >> 2, c4 = idx & 3;
      uint4 v = *(const uint4*)(Wb + col * 256 + kc * 32 + c4 * 8);
      *(uint4*)(Wlds + col * 40 + c4 * 8) = v;
    }
    __syncthreads();
    bf16x8 afr[2];
#pragma unroll
    for (int rt = 0; rt < 2; ++rt)
      afr[rt] = *(const bf16x8*)(Alds + (w * 32 + rt * 16 + l16) * 40 + q * 8);
    bf16x8 bfr[8];
#pragma unroll
    for (int ct = 0; ct < 8; ++ct)
      bfr[ct] = *(const bf16x8*)(Wlds + (ct * 16 + l16) * 40 + q * 8);
#pragma unroll
    for (int rt = 0; rt < 2; ++rt)
#pragma unroll
      for (int ct = 0; ct < 8; ++ct)
        acc[rt][ct] = __builtin_amdgcn_mfma_f32_16x16x32_bf16(
            afr[rt], bfr[ct], acc[rt][ct], 0, 0, 0);
    __syncthreads();
  }

  float bv[8];
#pragma unroll
  for (int ct = 0; ct < 8; ++ct) bv[ct] = b1[ct * 16 + l16];
#pragma unroll
  for (int rt = 0; rt < 2; ++rt) {
    int rbase = row0 + w * 32 + rt * 16 + q * 4;  // C layout: row=(lane>>4)*4+reg
#pragma unroll
    for (int reg = 0; reg < 4; ++reg) {
      float* hp = h + (size_t)(rbase + reg) * 128;
#pragma unroll
      for (int ct = 0; ct < 8; ++ct) {
        float v = acc[rt][ct][reg] + bv[ct];
        hp[ct * 16 + l16] = v > 0.f ? v : 0.f;
      }
    }
  }
}

// ---------------------------------------------------------------- layer-2 fold
// M[0:16]=Wc@W2l, M[16:32]=Wc@W2r (each 16x128), bias2 = Wc@b2l + bc
__global__ __launch_bounds__(256) void k_precomp(
    const float* __restrict__ Wc, const float* __restrict__ bc,
    const float* __restrict__ W2l, const float* __restrict__ W2r,
    const float* __restrict__ b2, float* __restrict__ M, float* __restrict__ bias2) {
  int b = blockIdx.x;  // 0..15
  int t = threadIdx.x;
  int mat = b >> 3;
  const float* W2 = mat ? W2r : W2l;
  int o = (b & 7) * 2 + (t >> 7);
  int k = t & 127;
  float s = 0.f;
  for (int j = 0; j < 128; ++j) s = fmaf(Wc[o * 128 + j], W2[j * 128 + k], s);
  M[(size_t)(mat * 16 + o) * 128 + k] = s;
  if (b == 0 && t < 16) {
    float sb = bc[t];
    for (int j = 0; j < 128; ++j) sb = fmaf(Wc[t * 128 + j], b2[j], sb);
    bias2[t] = sb;
  }
}

// P[N][32] = h @ M^T  (cols 0..15 feed aggregation, 16..31 self path)
__global__ __launch_bounds__(256) void k_gemm2(
    const float* __restrict__ h, const float* __restrict__ M,
    float* __restrict__ P, int N) {
  __shared__ float4 Ms[32][32];  // [k4][col] 16 KB
  __shared__ float4 As[64][32];  // [row][k4] 32 KB
  int t = threadIdx.x;
  int col = t & 31;
  int rg = t >> 5;
  int row0 = blockIdx.x * 64;
#pragma unroll
  for (int i = 0; i < 4; ++i) {
    int j = t + i * 256;
    int mc = j >> 5, k4 = j & 31;
    Ms[k4][mc] = *(const float4*)(M + (size_t)mc * 128 + k4 * 4);
  }
#pragma unroll
  for (int i = 0; i < 8; ++i) {
    int j = t + i * 256;
    int row = j >> 5, k4 = j & 31;
    As[row][k4] = *(const float4*)(h + (size_t)(row0 + row) * 128 + k4 * 4);
  }
  __syncthreads();
  float acc[8];
#pragma unroll
  for (int r = 0; r < 8; ++r) acc[r] = 0.f;
  for (int k4 = 0; k4 < 32; ++k4) {
    float4 w4 = Ms[k4][col];
#pragma unroll
    for (int r = 0; r < 8; ++r) {
      float4 a4 = As[rg * 8 + r][k4];
      acc[r] = fmaf(a4.x, w4.x, fmaf(a4.y, w4.y, fmaf(a4.z, w4.z, fmaf(a4.w, w4.w, acc[r]))));
    }
  }
#pragma unroll
  for (int r = 0; r < 8; ++r)
    P[(size_t)(row0 + rg * 8 + r) * 32 + col] = acc[r];
}

// out[i] = mean_nbr(P[src][0:16]) + P[i][16:32] + bias2 ; 16 lanes per node
__global__ __launch_bounds__(256) void k_agg2_out(
    const int* __restrict__ eidx, const int* __restrict__ cnt,
    const float* __restrict__ P, const float* __restrict__ bias2,
    float* __restrict__ out, int N) {
  int i = (blockIdx.x * 256 + threadIdx.x) >> 4;
  int f = threadIdx.x & 15;
  if (i >= N) return;
  int deg = cnt[i];
  const int* el = eidx + (size_t)i * CAP;
  float s = 0.f;
  int e = 0;
  for (; e + 4 <= deg; e += 4) {
    int4 q = *(const int4*)(el + e);
    s += P[(size_t)q.x * 32 + f] + P[(size_t)q.y * 32 + f] +
         P[(size_t)q.z * 32 + f] + P[(size_t)q.w * 32 + f];
  }
  for (; e < deg; ++e) s += P[(size_t)el[e] * 32 + f];
  float sc = 1.0f / (float)max(deg, 1);
  out[(size_t)i * 16 + f] = s * sc + P[(size_t)i * 32 + 16 + f] + bias2[f];
}

extern "C" void kernel_launch(void* const* d_in, const int* in_sizes, int n_in,
                              void* d_out, int out_size, void* d_ws, size_t ws_size,
                              hipStream_t stream) {
  const float* x   = (const float*)d_in[0];
  const int*   ei  = (const int*)d_in[1];
  const float* W1l = (const float*)d_in[2];
  const float* b1l = (const float*)d_in[3];
  const float* W1r = (const float*)d_in[4];
  const float* W2l = (const float*)d_in[5];
  const float* b2l = (const float*)d_in[6];
  const float* W2r = (const float*)d_in[7];
  const float* Wc  = (const float*)d_in[8];
  const float* bc  = (const float*)d_in[9];
  float* out = (float*)d_out;

  const int N    = in_sizes[0] / 128;
  const int E    = in_sizes[1] / 2;
  const int Np   = ((N + 127) / 128) * 128;   // pad to 128-row GEMM tiles
  const int Np64 = ((N + 63) / 64) * 64;
  const int nodes_per_part = (N + NPART - 1) / NPART;

  char* ws = (char*)d_ws;
  size_t off = 0;
  auto alloc = [&](size_t bytes) {
    void* p = ws + off;
    off = (off + bytes + 255) & ~(size_t)255;
    return p;
  };
  int*            cnt   = (int*)           alloc((size_t)N * 4);
  int*            eidx  = (int*)           alloc((size_t)N * CAP * 4);
  unsigned short* xb    = (unsigned short*)alloc((size_t)Np * 128 * 2);
  unsigned short* aggb  = (unsigned short*)alloc((size_t)Np * 128 * 2);
  unsigned short* Wb    = (unsigned short*)alloc((size_t)128 * 256 * 2);
  float*          h     = (float*)         alloc((size_t)Np * 128 * 4);
  float*          P     = (float*)         alloc((size_t)Np * 32 * 4);
  float*          M     = (float*)         alloc((size_t)32 * 128 * 4);
  float*          bias2 = (float*)         alloc(16 * 4);
  (void)ws_size; (void)n_in; (void)out_size;

  hipMemsetAsync(cnt, 0, (size_t)N * 4, stream);
  k_fill_part<<<NPART * 128, 256, 0, stream>>>(ei, E, nodes_per_part, cnt, eidx);
  k_cast<<<(N * 32 + 255) / 256, 256, 0, stream>>>(x, xb, N * 32);
  k_castW<<<128, 256, 0, stream>>>(W1l, W1r, Wb);
  k_precomp<<<16, 256, 0, stream>>>(Wc, bc, W2l, W2r, b2l, M, bias2);
  k_agg1<<<(N + 3) / 4, 256, 0, stream>>>(eidx, cnt, xb, aggb, N);
  k_gemm1_mfma<<<Np / 128, 256, 0, stream>>>(aggb, xb, Wb, b1l, h, N);
  k_gemm2<<<Np64 / 64, 256, 0, stream>>>(h, M, P, N);
  k_agg2_out<<<(N + 15) / 16, 256, 0, stream>>>(eidx, cnt, P, bias2, out, N);
}

// Round 4
// 350.173 us; speedup vs baseline: 1.4197x; 1.0212x over previous
//
#include <hip/hip_runtime.h>

#define CAP 64    // per-node edge capacity (Poisson(16): P(deg>64) ~ 1e-19)
#define NPART 8   // one dst-range partition per XCD (blockIdx % 8 ~ XCD id)

typedef __bf16 bf16x8 __attribute__((ext_vector_type(8)));
typedef float  f32x4  __attribute__((ext_vector_type(4)));
typedef int    i32x4  __attribute__((ext_vector_type(4)));

__device__ __forceinline__ unsigned short f2b(float f) {  // fp32 -> bf16 RNE
  unsigned u = __float_as_uint(f);
  return (unsigned short)((u + 0x7fffu + ((u >> 16) & 1u)) >> 16);
}
__device__ __forceinline__ float b2f_lo(unsigned u) {  // low bf16 of packed pair
  return __uint_as_float(u << 16);
}
__device__ __forceinline__ float b2f_hi(unsigned u) {
  return __uint_as_float(u & 0xffff0000u);
}

// ---------------------------------------------------------------- CSR build
// nt loads on the src/dst streams: evict-first in L2 so the partition's
// eidx write set (3.2 MB < 4 MB XCD L2) stays resident and stores merge.
__global__ __launch_bounds__(256) void k_fill_part(
    const int* __restrict__ ei, int E, int nodes_per_part,
    int* __restrict__ cnt, int* __restrict__ eidx) {
  const int part = blockIdx.x & (NPART - 1);
  const int cb = blockIdx.x >> 3;
  const int ncb = gridDim.x >> 3;
  const int lo = part * nodes_per_part;
  const int hi = lo + nodes_per_part;
  const int* __restrict__ src = ei;
  const int* __restrict__ dst = ei + E;
  const int G = E >> 2;
  for (int g = cb * 256 + threadIdx.x; g < G; g += ncb * 256) {
    i32x4 d4 = __builtin_nontemporal_load((const i32x4*)dst + g);
    int e0 = g * 4;
    if (d4.x >= lo && d4.x < hi) {
      int p = atomicAdd(&cnt[d4.x], 1);
      if (p < CAP) eidx[(size_t)d4.x * CAP + p] = __builtin_nontemporal_load(src + e0);
    }
    if (d4.y >= lo && d4.y < hi) {
      int p = atomicAdd(&cnt[d4.y], 1);
      if (p < CAP) eidx[(size_t)d4.y * CAP + p] = __builtin_nontemporal_load(src + e0 + 1);
    }
    if (d4.z >= lo && d4.z < hi) {
      int p = atomicAdd(&cnt[d4.z], 1);
      if (p < CAP) eidx[(size_t)d4.z * CAP + p] = __builtin_nontemporal_load(src + e0 + 2);
    }
    if (d4.w >= lo && d4.w < hi) {
      int p = atomicAdd(&cnt[d4.w], 1);
      if (p < CAP) eidx[(size_t)d4.w * CAP + p] = __builtin_nontemporal_load(src + e0 + 3);
    }
  }
  if (cb == 0) {
    for (int e = G * 4 + threadIdx.x; e < E; e += 256) {
      int d = dst[e];
      if (d >= lo && d < hi) {
        int p = atomicAdd(&cnt[d], 1);
        if (p < CAP) eidx[(size_t)d * CAP + p] = src[e];
      }
    }
  }
}

// ---------------------------------------------------------------- casts
// x (fp32) -> xb (bf16), one float4 per thread
__global__ __launch_bounds__(256) void k_cast(
    const float* __restrict__ x, unsigned short* __restrict__ xb, int ngroups) {
  int g = blockIdx.x * 256 + threadIdx.x;
  if (g >= ngroups) return;
  float4 v = ((const float4*)x)[g];
  ushort4 o;
  o.x = f2b(v.x); o.y = f2b(v.y); o.z = f2b(v.z); o.w = f2b(v.w);
  ((ushort4*)xb)[g] = o;
}

// Wb[col][k] bf16, k<128 from W1l, k>=128 from W1r (both stored [col][k] fp32)
__global__ __launch_bounds__(256) void k_castW(
    const float* __restrict__ W1l, const float* __restrict__ W1r,
    unsigned short* __restrict__ Wb) {
  int idx = blockIdx.x * 256 + threadIdx.x;  // 128*256 = 32768 total
  int col = idx >> 8, k = idx & 255;
  float v = (k < 128) ? W1l[col * 128 + k] : W1r[col * 128 + (k - 128)];
  Wb[col * 256 + k] = f2b(v);
}

// ---------------------------------------------------------------- agg1 (bf16)
// aggb[i] = bf16(mean over neighbors of xb[src]); lane handles bf16 pair lane*2
__global__ __launch_bounds__(256) void k_agg1(
    const int* __restrict__ eidx, const int* __restrict__ cnt,
    const unsigned short* __restrict__ xb, unsigned short* __restrict__ aggb, int N) {
  int w = (blockIdx.x * 256 + threadIdx.x) >> 6;
  int lane = threadIdx.x & 63;
  if (w >= N) return;
  int deg = cnt[w];
  const int* el = eidx + (size_t)w * CAP;
  float s0 = 0.f, s1 = 0.f;
  int e = 0;
  for (; e + 4 <= deg; e += 4) {
    int4 q = *(const int4*)(el + e);
    unsigned u0 = *(const unsigned*)(xb + (size_t)q.x * 128 + lane * 2);
    unsigned u1 = *(const unsigned*)(xb + (size_t)q.y * 128 + lane * 2);
    unsigned u2 = *(const unsigned*)(xb + (size_t)q.z * 128 + lane * 2);
    unsigned u3 = *(const unsigned*)(xb + (size_t)q.w * 128 + lane * 2);
    s0 += b2f_lo(u0) + b2f_lo(u1) + b2f_lo(u2) + b2f_lo(u3);
    s1 += b2f_hi(u0) + b2f_hi(u1) + b2f_hi(u2) + b2f_hi(u3);
  }
  for (; e < deg; ++e) {
    unsigned u = *(const unsigned*)(xb + (size_t)el[e] * 128 + lane * 2);
    s0 += b2f_lo(u); s1 += b2f_hi(u);
  }
  float sc = 1.0f / (float)max(deg, 1);
  unsigned o = (unsigned)f2b(s0 * sc) | ((unsigned)f2b(s1 * sc) << 16);
  *(unsigned*)(aggb + (size_t)w * 128 + lane * 2) = o;
}

// ---------------------------------------------------------------- gemm1 MFMA
// h = relu([aggb | xb] @ Wb^T + b1)  (K=256, bf16 in / fp32 out)
// Block: 128 rows x 128 cols, 4 waves; wave w owns rows [w*32, w*32+32).
// LDS rows padded to 40 bf16 (80 B) -> <=2-way bank aliasing (free, m136).
__global__ __launch_bounds__(256) void k_gemm1_mfma(
    const unsigned short* __restrict__ aggb, const unsigned short* __restrict__ xb,
    const unsigned short* __restrict__ Wb, const float* __restrict__ b1,
    float* __restrict__ h, int N) {
  __shared__ unsigned short Alds[128 * 40];  // 10 KB
  __shared__ unsigned short Wlds[128 * 40];  // 10 KB
  const int t = threadIdx.x;
  const int w = t >> 6;
  const int lane = t & 63;
  const int q = lane >> 4;       // k-quad of the fragment
  const int l16 = lane & 15;
  const int row0 = blockIdx.x * 128;

  f32x4 acc[2][8];
#pragma unroll
  for (int rt = 0; rt < 2; ++rt)
#pragma unroll
    for (int ct = 0; ct < 8; ++ct) acc[rt][ct] = (f32x4){0.f, 0.f, 0.f, 0.f};

  for (int kc = 0; kc < 8; ++kc) {
    const unsigned short* Asrc = (kc < 4) ? aggb : xb;
    const int koff = (kc & 3) * 32;
#pragma unroll
    for (int i = 0; i < 2; ++i) {  // stage A: 128 rows x 32 k (8 KB)
      int idx = t + i * 256;
      int row = idx >> 2, c4 = idx & 3;
      int gr = row0 + row; if (gr >= N) gr = N - 1;
      uint4 v = *(const uint4*)(Asrc + (size_t)gr * 128 + koff + c4 * 8);
      *(uint4*)(Alds + row * 40 + c4 * 8) = v;
    }
#pragma unroll
    for (int i = 0; i < 2; ++i) {  // stage W: 128 cols x 32 k (8 KB)
      int idx = t + i * 256;
      int col = idx >> 2, c4 = idx & 3;
      uint4 v = *(const uint4*)(Wb + col * 256 + kc * 32 + c4 * 8);
      *(uint4*)(Wlds + col * 40 + c4 * 8) = v;
    }
    __syncthreads();
    bf16x8 afr[2];
#pragma unroll
    for (int rt = 0; rt < 2; ++rt)
      afr[rt] = *(const bf16x8*)(Alds + (w * 32 + rt * 16 + l16) * 40 + q * 8);
    bf16x8 bfr[8];
#pragma unroll
    for (int ct = 0; ct < 8; ++ct)
      bfr[ct] = *(const bf16x8*)(Wlds + (ct * 16 + l16) * 40 + q * 8);
#pragma unroll
    for (int rt = 0; rt < 2; ++rt)
#pragma unroll
      for (int ct = 0; ct < 8; ++ct)
        acc[rt][ct] = __builtin_amdgcn_mfma_f32_16x16x32_bf16(
            afr[rt], bfr[ct], acc[rt][ct], 0, 0, 0);
    __syncthreads();
  }

  float bv[8];
#pragma unroll
  for (int ct = 0; ct < 8; ++ct) bv[ct] = b1[ct * 16 + l16];
#pragma unroll
  for (int rt = 0; rt < 2; ++rt) {
    int rbase = row0 + w * 32 + rt * 16 + q * 4;  // C layout: row=(lane>>4)*4+reg
#pragma unroll
    for (int reg = 0; reg < 4; ++reg) {
      float* hp = h + (size_t)(rbase + reg) * 128;
#pragma unroll
      for (int ct = 0; ct < 8; ++ct) {
        float v = acc[rt][ct][reg] + bv[ct];
        hp[ct * 16 + l16] = v > 0.f ? v : 0.f;
      }
    }
  }
}

// ---------------------------------------------------------------- layer-2 fold
// M[0:16]=Wc@W2l, M[16:32]=Wc@W2r (each 16x128), bias2 = Wc@b2l + bc
__global__ __launch_bounds__(256) void k_precomp(
    const float* __restrict__ Wc, const float* __restrict__ bc,
    const float* __restrict__ W2l, const float* __restrict__ W2r,
    const float* __restrict__ b2, float* __restrict__ M, float* __restrict__ bias2) {
  int b = blockIdx.x;  // 0..15
  int t = threadIdx.x;
  int mat = b >> 3;
  const float* W2 = mat ? W2r : W2l;
  int o = (b & 7) * 2 + (t >> 7);
  int k = t & 127;
  float s = 0.f;
  for (int j = 0; j < 128; ++j) s = fmaf(Wc[o * 128 + j], W2[j * 128 + k], s);
  M[(size_t)(mat * 16 + o) * 128 + k] = s;
  if (b == 0 && t < 16) {
    float sb = bc[t];
    for (int j = 0; j < 128; ++j) sb = fmaf(Wc[t * 128 + j], b2[j], sb);
    bias2[t] = sb;
  }
}

// P[N][32] = h @ M^T  (cols 0..15 feed aggregation, 16..31 self path)
__global__ __launch_bounds__(256) void k_gemm2(
    const float* __restrict__ h, const float* __restrict__ M,
    float* __restrict__ P, int N) {
  __shared__ float4 Ms[32][32];  // [k4][col] 16 KB
  __shared__ float4 As[64][32];  // [row][k4] 32 KB
  int t = threadIdx.x;
  int col = t & 31;
  int rg = t >> 5;
  int row0 = blockIdx.x * 64;
#pragma unroll
  for (int i = 0; i < 4; ++i) {
    int j = t + i * 256;
    int mc = j >> 5, k4 = j & 31;
    Ms[k4][mc] = *(const float4*)(M + (size_t)mc * 128 + k4 * 4);
  }
#pragma unroll
  for (int i = 0; i < 8; ++i) {
    int j = t + i * 256;
    int row = j >> 5, k4 = j & 31;
    As[row][k4] = *(const float4*)(h + (size_t)(row0 + row) * 128 + k4 * 4);
  }
  __syncthreads();
  float acc[8];
#pragma unroll
  for (int r = 0; r < 8; ++r) acc[r] = 0.f;
  for (int k4 = 0; k4 < 32; ++k4) {
    float4 w4 = Ms[k4][col];
#pragma unroll
    for (int r = 0; r < 8; ++r) {
      float4 a4 = As[rg * 8 + r][k4];
      acc[r] = fmaf(a4.x, w4.x, fmaf(a4.y, w4.y, fmaf(a4.z, w4.z, fmaf(a4.w, w4.w, acc[r]))));
    }
  }
#pragma unroll
  for (int r = 0; r < 8; ++r)
    P[(size_t)(row0 + rg * 8 + r) * 32 + col] = acc[r];
}

// out[i] = mean_nbr(P[src][0:16]) + P[i][16:32] + bias2 ; 16 lanes per node
__global__ __launch_bounds__(256) void k_agg2_out(
    const int* __restrict__ eidx, const int* __restrict__ cnt,
    const float* __restrict__ P, const float* __restrict__ bias2,
    float* __restrict__ out, int N) {
  int i = (blockIdx.x * 256 + threadIdx.x) >> 4;
  int f = threadIdx.x & 15;
  if (i >= N) return;
  int deg = cnt[i];
  const int* el = eidx + (size_t)i * CAP;
  float s = 0.f;
  int e = 0;
  for (; e + 4 <= deg; e += 4) {
    int4 q = *(const int4*)(el + e);
    s += P[(size_t)q.x * 32 + f] + P[(size_t)q.y * 32 + f] +
         P[(size_t)q.z * 32 + f] + P[(size_t)q.w * 32 + f];
  }
  for (; e < deg; ++e) s += P[(size_t)el[e] * 32 + f];
  float sc = 1.0f / (float)max(deg, 1);
  out[(size_t)i * 16 + f] = s * sc + P[(size_t)i * 32 + 16 + f] + bias2[f];
}

extern "C" void kernel_launch(void* const* d_in, const int* in_sizes, int n_in,
                              void* d_out, int out_size, void* d_ws, size_t ws_size,
                              hipStream_t stream) {
  const float* x   = (const float*)d_in[0];
  const int*   ei  = (const int*)d_in[1];
  const float* W1l = (const float*)d_in[2];
  const float* b1l = (const float*)d_in[3];
  const float* W1r = (const float*)d_in[4];
  const float* W2l = (const float*)d_in[5];
  const float* b2l = (const float*)d_in[6];
  const float* W2r = (const float*)d_in[7];
  const float* Wc  = (const float*)d_in[8];
  const float* bc  = (const float*)d_in[9];
  float* out = (float*)d_out;

  const int N    = in_sizes[0] / 128;
  const int E    = in_sizes[1] / 2;
  const int Np   = ((N + 127) / 128) * 128;   // pad to 128-row GEMM tiles
  const int Np64 = ((N + 63) / 64) * 64;
  const int nodes_per_part = (N + NPART - 1) / NPART;

  char* ws = (char*)d_ws;
  size_t off = 0;
  auto alloc = [&](size_t bytes) {
    void* p = ws + off;
    off = (off + bytes + 255) & ~(size_t)255;
    return p;
  };
  int*            cnt   = (int*)           alloc((size_t)N * 4);
  int*            eidx  = (int*)           alloc((size_t)N * CAP * 4);
  unsigned short* xb    = (unsigned short*)alloc((size_t)Np * 128 * 2);
  unsigned short* aggb  = (unsigned short*)alloc((size_t)Np * 128 * 2);
  unsigned short* Wb    = (unsigned short*)alloc((size_t)128 * 256 * 2);
  float*          h     = (float*)         alloc((size_t)Np * 128 * 4);
  float*          P     = (float*)         alloc((size_t)Np * 32 * 4);
  float*          M     = (float*)         alloc((size_t)32 * 128 * 4);
  float*          bias2 = (float*)         alloc(16 * 4);
  (void)ws_size; (void)n_in; (void)out_size;

  hipMemsetAsync(cnt, 0, (size_t)N * 4, stream);
  // 8 partitions x 256 edge-chunks (VGPR=12/LDS=0 -> occupancy-capped at 32 waves/CU)
  k_fill_part<<<NPART * 256, 256, 0, stream>>>(ei, E, nodes_per_part, cnt, eidx);
  k_cast<<<(N * 32 + 255) / 256, 256, 0, stream>>>(x, xb, N * 32);
  k_castW<<<128, 256, 0, stream>>>(W1l, W1r, Wb);
  k_precomp<<<16, 256, 0, stream>>>(Wc, bc, W2l, W2r, b2l, M, bias2);
  k_agg1<<<(N + 3) / 4, 256, 0, stream>>>(eidx, cnt, xb, aggb, N);
  k_gemm1_mfma<<<Np / 128, 256, 0, stream>>>(aggb, xb, Wb, b1l, h, N);
  k_gemm2<<<Np64 / 64, 256, 0, stream>>>(h, M, P, N);
  k_agg2_out<<<(N + 15) / 16, 256, 0, stream>>>(eidx, cnt, P, bias2, out, N);
}